// Round 4
// baseline (132.806 us; speedup 1.0000x reference)
//
#include <hip/hip_runtime.h>

typedef unsigned short u16;
typedef unsigned int u32;
typedef __bf16 bf16x8 __attribute__((ext_vector_type(8)));
typedef float f32x16 __attribute__((ext_vector_type(16)));

#define C2 (-7.213475204444817f) /* -5/ln2 : exp(-5 t^2) = exp2(C2 t^2) */
#define T1C 0.28650480f          /* e^-1.25 */
#define T2C 0.0067379470f        /* e^-5    */

__device__ __forceinline__ u16 f2bf(float f) {
  u32 u = __float_as_uint(f);
  return (u16)((u + 0x7FFFu + ((u >> 16) & 1u)) >> 16);  // RNE
}

__device__ __forceinline__ f32x16 mfma16(uint4 a, uint4 b, f32x16 c) {
  return __builtin_amdgcn_mfma_f32_32x32x16_bf16(
      __builtin_bit_cast(bf16x8, a), __builtin_bit_cast(bf16x8, b), c, 0, 0, 0);
}

// ---------------------------------------------------------------------------
// Prep (unchanged; validated): f32 weights -> bf16, per-16k-chunk fragment
// order. wst3 granule(c, g) 16 B, g = s*256 + nq*64 + l:
//   content = W_s[k = c*16 + (l>>5)*8 + 0..8)[u = nq*32 + (l&31)]
// ---------------------------------------------------------------------------
__global__ __launch_bounds__(256) void kan_prep(const float* __restrict__ wb,
                                                const float* __restrict__ ws,
                                                u16* __restrict__ wst3) {
  __shared__ u16 tile[6][16][130];
  const int t = threadIdx.x;
  const int c = blockIdx.x;
#pragma unroll
  for (int it = 0; it < 8; ++it) {
    int idx = it * 256 + t;
    int d = idx >> 7, u = idx & 127;
    size_t base = (size_t)(c * 16 + d) * 128 + u;
    const float* p = ws + base * 8;
    float4 v0 = *(const float4*)p;
    float g4 = p[4];
    tile[0][d][u] = f2bf(v0.x);
    tile[1][d][u] = f2bf(v0.y);
    tile[2][d][u] = f2bf(v0.z);
    tile[3][d][u] = f2bf(v0.w);
    tile[4][d][u] = f2bf(g4);
    tile[5][d][u] = f2bf(wb[base]);
  }
  __syncthreads();
#pragma unroll
  for (int i = 0; i < 6; ++i) {
    int g = i * 256 + t;
    int s = g >> 8, r = g & 255;
    int nq = r >> 6, l = r & 63;
    int u = nq * 32 + (l & 31);
    int dbase = (l >> 5) * 8;
    u32 q[4];
#pragma unroll
    for (int j = 0; j < 4; ++j) {
      u32 lo = tile[s][dbase + 2 * j][u];
      u32 hi = tile[s][dbase + 2 * j + 1][u];
      q[j] = lo | (hi << 16);
    }
    uint4 w4; w4.x = q[0]; w4.y = q[1]; w4.z = q[2]; w4.w = q[3];
    *(uint4*)(wst3 + (size_t)c * 12288 + (size_t)g * 8) = w4;
  }
}

// ---------------------------------------------------------------------------
// Main R12: ring-6 LDS pipeline, barrier every 3 bodies.  256 blocks x 512
// thr, M=64, full N=128.  32 bodies of BK=32 (2 c16 chunks each); slab =
// 24 KB, ring 6 x 24576 = 144 KB.  slot(body) = body%6 = 3*(j&1)+b for
// window j (bodies 3j..3j+2), so producers (write 3j+3..3j+5) and consumers
// (read 3j..3j+2) touch disjoint slot triples; ONE barrier per window
// (13 total incl prologue+epilogue vs R11's 17, and 3 independent bodies
// of runway between barriers).
// Waves 0..3 = producers: wave w owns k-octet o2=w of every body, lane owns
// row r=lane.  Granule (s,g,p=chunk,h=octet-half) at byte s*4096 +
// (g*2+p)*1024 + h*512 + ((m^(p*2+h))&31)*16  (XOR swizzle, conflict-free
// both sides; same family as validated R8/R11 layouts).
// Waves 4..7 = consumers (wn = n-half, kc = chunk-in-body): tile 64m x 64n
// x k-half, acc 8 x f32x16 ([g*2+nq] spline, [4+...] base); B direct from
// L2 (fragment-ordered wst3).  2-way k-merge epilogue (kc=1 -> LDS -> kc=0),
// then silu+add+store.  mfma A[m=lane&31][k=(lane>>5)*8+j]; C/D col=lane&31,
// row=(reg&3)+8*(reg>>2)+4*(lane>>5)   (all validated R2-R11).
// ---------------------------------------------------------------------------
__global__ __launch_bounds__(512, 2) void kan_main(const float* __restrict__ x,
                                                   const u16* __restrict__ wst3,
                                                   float* __restrict__ out) {
  __shared__ __align__(16) char lds[147456];  // 6 x 24576 ring

  const int t = threadIdx.x;
  const int lane = t & 63;
  const int w = t >> 6;
  const int b0 = blockIdx.x * 64;

  if (w < 4) {
    // ================= PRODUCERS =================
    const int r = lane;   // row 0..63
    const int o2 = w;     // k-octet 0..3 within body's 32k
    const int g = r >> 5, m = r & 31;
    const u32 aw = (u32)(((g * 2 + (o2 >> 1)) << 10) + ((o2 & 1) << 9) +
                         (((m ^ o2) & 31) << 4));
    const float* xp = x + (size_t)(b0 + r) * 1024 + o2 * 8;

    auto rbf6 = [&](char* dst, float4 va, float4 vb) {
      float xf[8] = {va.x, va.y, va.z, va.w, vb.x, vb.y, vb.z, vb.w};
      u32 pk[6][4];
#pragma unroll
      for (int pp = 0; pp < 4; ++pp) {
        u32 lo6[6], hi6[6];
#pragma unroll
        for (int e = 0; e < 2; ++e) {
          float xv = xf[2 * pp + e];
          float t0 = C2 * xv;
          float P = __builtin_amdgcn_exp2f(t0 * xv);  // e^{-5x^2}
          float Qp = __builtin_amdgcn_exp2f(-t0);     // e^{+5x}
          float Qm = __builtin_amdgcn_exp2f(t0);      // e^{-5x}
          float PQ = P * Qp, PQm = P * Qm;
          u32* d = e ? hi6 : lo6;
          d[0] = __float_as_uint(PQm * Qm * T2C) + 0x8000u;
          d[1] = __float_as_uint(PQm * T1C) + 0x8000u;
          d[2] = __float_as_uint(P) + 0x8000u;
          d[3] = __float_as_uint(PQ * T1C) + 0x8000u;
          d[4] = __float_as_uint(PQ * Qp * T2C) + 0x8000u;
          d[5] = __float_as_uint(xv) + 0x8000u;
        }
#pragma unroll
        for (int s = 0; s < 6; ++s)
          pk[s][pp] = __builtin_amdgcn_perm(hi6[s], lo6[s], 0x07060302);
      }
#pragma unroll
      for (int s = 0; s < 6; ++s) {
        uint4 v; v.x = pk[s][0]; v.y = pk[s][1]; v.z = pk[s][2]; v.w = pk[s][3];
        *(uint4*)(dst + s * 4096) = v;
      }
    };

    // depth-2 x prefetch (bodies are produced strictly in order 0..31)
    float4 xa = *(const float4*)xp;
    float4 xb = *(const float4*)(xp + 4);
    float4 na = *(const float4*)(xp + 32);
    float4 nb = *(const float4*)(xp + 36);

    auto produce = [&](int body, int slot) {
      rbf6(lds + slot * 24576 + aw, xa, xb);
      xa = na; xb = nb;
      if (body + 2 < 32) {
        na = *(const float4*)(xp + (body + 2) * 32);
        nb = *(const float4*)(xp + (body + 2) * 32 + 4);
      }
    };

    produce(0, 0); produce(1, 1); produce(2, 2);
    __syncthreads();  // barrier #1
    for (int j = 0; j < 11; ++j) {
      const int ps = (j & 1) ? 0 : 3;  // slot base for bodies 3j+3..3j+5
#pragma unroll
      for (int bq = 0; bq < 3; ++bq) {
        int body = 3 * j + 3 + bq;
        if (body < 32) produce(body, ps + bq);
      }
      __syncthreads();  // barriers #2..#12
    }
    __syncthreads();  // barrier #13 (epilogue stage; producers just match)
  } else {
    // ================= CONSUMERS =================
    const int c = w - 4;
    const int wn = c & 1;   // n-half: cols wn*64 .. +64
    const int kc = c >> 1;  // chunk-in-body (k-half of BK=32)
    const int m = lane & 31, hh = lane >> 5;
    const u32 ar0 = (u32)((kc << 10) + (hh << 9) +
                          (((m ^ (kc * 2 + hh)) & 31) << 4));  // g=0
    const u32 ar1 = ar0 + 2048;                                // g=1
    const char* bb =
        (const char*)wst3 + (size_t)kc * 24576 + wn * 2048 + lane * 16;

    f32x16 acc[8];
#pragma unroll
    for (int i = 0; i < 8; ++i)
#pragma unroll
      for (int jj = 0; jj < 16; ++jj) acc[i][jj] = 0.f;

    __syncthreads();  // barrier #1
    for (int j = 0; j < 11; ++j) {
      const int cs = (j & 1) ? 3 : 0;  // slot base for bodies 3j..3j+2
#pragma unroll
      for (int bq = 0; bq < 3; ++bq) {
        int body = 3 * j + bq;
        if (body < 32) {
          const char* ab = lds + (cs + bq) * 24576;
          const char* bby = bb + (size_t)body * 49152;  // chunk 2*body+kc
#pragma unroll
          for (int h = 0; h < 2; ++h) {  // slabs 0..2, then 3..5
            uint4 bv0[3], bv1[3], a0[3], a1[3];
#pragma unroll
            for (int si = 0; si < 3; ++si) {
              int s = h * 3 + si;
              bv0[si] = *(const uint4*)(bby + s * 4096);
              bv1[si] = *(const uint4*)(bby + s * 4096 + 1024);
              a0[si] = *(const uint4*)(ab + s * 4096 + ar0);
              a1[si] = *(const uint4*)(ab + s * 4096 + ar1);
            }
            __builtin_amdgcn_s_setprio(1);
#pragma unroll
            for (int si = 0; si < 3; ++si) {
              int s = h * 3 + si;
              int bi = (s < 5) ? 0 : 4;  // slab 5 = base path
              acc[bi + 0] = mfma16(a0[si], bv0[si], acc[bi + 0]);
              acc[bi + 1] = mfma16(a0[si], bv1[si], acc[bi + 1]);
              acc[bi + 2] = mfma16(a1[si], bv0[si], acc[bi + 2]);
              acc[bi + 3] = mfma16(a1[si], bv1[si], acc[bi + 3]);
            }
            __builtin_amdgcn_s_setprio(0);
          }
        }
      }
      __syncthreads();  // barriers #2..#12
    }

    // ---- epilogue: 2-way k-merge (kc=1 -> LDS; kc=0 merges+silu+stores)
    if (kc == 1) {
      char* slab = lds + wn * 32768;
#pragma unroll
      for (int a = 0; a < 8; ++a)
#pragma unroll
        for (int rq = 0; rq < 4; ++rq)
          *(float4*)(slab + a * 4096 + rq * 1024 + lane * 16) =
              make_float4(acc[a][4 * rq], acc[a][4 * rq + 1],
                          acc[a][4 * rq + 2], acc[a][4 * rq + 3]);
    }
    __syncthreads();  // barrier #13
    if (kc == 0) {
      const char* slab = lds + wn * 32768;
#pragma unroll
      for (int a = 0; a < 8; ++a)
#pragma unroll
        for (int rq = 0; rq < 4; ++rq) {
          float4 v = *(const float4*)(slab + a * 4096 + rq * 1024 + lane * 16);
          acc[a][4 * rq] += v.x; acc[a][4 * rq + 1] += v.y;
          acc[a][4 * rq + 2] += v.z; acc[a][4 * rq + 3] += v.w;
        }
#pragma unroll
      for (int g2 = 0; g2 < 2; ++g2)
#pragma unroll
        for (int nq = 0; nq < 2; ++nq) {
          int ai = g2 * 2 + nq;
          int col = wn * 64 + nq * 32 + (lane & 31);
#pragma unroll
          for (int reg = 0; reg < 16; ++reg) {
            int row = g2 * 32 + (reg & 3) + 8 * (reg >> 2) + 4 * (lane >> 5);
            float z = acc[4 + ai][reg];
            float sv = z / (1.0f + __expf(-z));
            out[(size_t)(b0 + row) * 128 + col] = sv + acc[ai][reg];
          }
        }
    }
  }
}

extern "C" void kernel_launch(void* const* d_in, const int* in_sizes, int n_in,
                              void* d_out, int out_size, void* d_ws, size_t ws_size,
                              hipStream_t stream) {
  const float* x  = (const float*)d_in[0];   // [16384][1024] f32
  const float* wb = (const float*)d_in[1];   // [1024][128]   f32
  const float* ws = (const float*)d_in[2];   // [1024][128][8] f32
  u16* wst3 = (u16*)d_ws;                    // [64][1536] granules, 1.5 MB
  float* out = (float*)d_out;                // [16384][128]  f32

  kan_prep<<<dim3(64), 256, 0, stream>>>(wb, ws, wst3);
  kan_main<<<dim3(256), 512, 0, stream>>>(x, wst3, out);
}

// Round 6
// 129.099 us; speedup vs baseline: 1.0287x; 1.0287x over previous
//
#include <hip/hip_runtime.h>

typedef unsigned short u16;
typedef unsigned int u32;
typedef __bf16 bf16x8 __attribute__((ext_vector_type(8)));
typedef float f32x16 __attribute__((ext_vector_type(16)));

#define C2 (-7.213475204444817f) /* -5/ln2 : exp(-5 t^2) = exp2(C2 t^2) */
#define T1C 0.28650480f          /* e^-1.25 */
#define T2C 0.0067379470f        /* e^-5    */

__device__ __forceinline__ u16 f2bf(float f) {
  u32 u = __float_as_uint(f);
  return (u16)((u + 0x7FFFu + ((u >> 16) & 1u)) >> 16);  // RNE
}

__device__ __forceinline__ f32x16 mfma16(uint4 a, uint4 b, f32x16 c) {
  return __builtin_amdgcn_mfma_f32_32x32x16_bf16(
      __builtin_bit_cast(bf16x8, a), __builtin_bit_cast(bf16x8, b), c, 0, 0, 0);
}

// ---------------------------------------------------------------------------
// Prep (unchanged; validated): f32 weights -> bf16, per-16k-chunk fragment
// order. wst3 granule(c, g) 16 B, g = s*256 + nq*64 + l:
//   content = W_s[k = c*16 + (l>>5)*8 + 0..8)[u = nq*32 + (l&31)]
// ---------------------------------------------------------------------------
__global__ __launch_bounds__(256) void kan_prep(const float* __restrict__ wb,
                                                const float* __restrict__ ws,
                                                u16* __restrict__ wst3) {
  __shared__ u16 tile[6][16][130];
  const int t = threadIdx.x;
  const int c = blockIdx.x;
#pragma unroll
  for (int it = 0; it < 8; ++it) {
    int idx = it * 256 + t;
    int d = idx >> 7, u = idx & 127;
    size_t base = (size_t)(c * 16 + d) * 128 + u;
    const float* p = ws + base * 8;
    float4 v0 = *(const float4*)p;
    float g4 = p[4];
    tile[0][d][u] = f2bf(v0.x);
    tile[1][d][u] = f2bf(v0.y);
    tile[2][d][u] = f2bf(v0.z);
    tile[3][d][u] = f2bf(v0.w);
    tile[4][d][u] = f2bf(g4);
    tile[5][d][u] = f2bf(wb[base]);
  }
  __syncthreads();
#pragma unroll
  for (int i = 0; i < 6; ++i) {
    int g = i * 256 + t;
    int s = g >> 8, r = g & 255;
    int nq = r >> 6, l = r & 63;
    int u = nq * 32 + (l & 31);
    int dbase = (l >> 5) * 8;
    u32 q[4];
#pragma unroll
    for (int j = 0; j < 4; ++j) {
      u32 lo = tile[s][dbase + 2 * j][u];
      u32 hi = tile[s][dbase + 2 * j + 1][u];
      q[j] = lo | (hi << 16);
    }
    uint4 w4; w4.x = q[0]; w4.y = q[1]; w4.z = q[2]; w4.w = q[3];
    *(uint4*)(wst3 + (size_t)c * 12288 + (size_t)g * 8) = w4;
  }
}

// ---------------------------------------------------------------------------
// Main R13 (resubmit; round-5 bench was an infra failure, kernel audited
// clean): 768 thr = 12 waves, 3/SIMD: per SIMD 1 producer + 2 consumers.
// Producers (waves 0..3): verbatim R11 rbf pipeline — wave w owns k-octet
// o of BK=64 body, lane owns rows r0 and r0+32; rbf once per block; LDS
// dbuf 2 x 48 KB, one barrier per body (16 bodies).
// Consumers (waves 4..11): wn = n-quad (32 cols), kc = k-half (512 k).
// acc 4 x f32x16 = 64 AGPR ([0,1]=spline g0/g1, [2,3]=base).  Per body:
// 2 chunks (p = kc*2+pl): 6 B dwordx4 from L2 (fragment-ordered wst3),
// 12 A b128 from LDS, 12 MFMA in setprio(1).  TWO consumer waves per SIMD
// cover each other's B-latency + MFMA dependency stalls (the R11 single-
// consumer structural stall).  Epilogue: kc=1 -> LDS (64 KB), kc=0 merges
// + silu + store.  Layouts all validated R2-R12:
// A granule (s,g,p,kh): byte s*8192 + (g*4+p)*1024 + kh*512 +
//   ((m^(p*2+kh))&31)*16;  B byte cc*24576 + s*4096 + wn*1024 + lane*16;
// mfma A[m=lane&31][k=(lane>>5)*8+j]; C/D col=lane&31,
// row=(reg&3)+8*(reg>>2)+4*(lane>>5).
// ---------------------------------------------------------------------------
__global__ __launch_bounds__(768, 3) void kan_main(const float* __restrict__ x,
                                                   const u16* __restrict__ wst3,
                                                   float* __restrict__ out) {
  __shared__ __align__(16) char lds[98304];  // 2 x 49152

  const int t = threadIdx.x;
  const int lane = t & 63;
  const int w = t >> 6;
  const int b0 = blockIdx.x * 64;

  if (w < 4) {
    // ================= PRODUCERS =================
    const int pid = (w << 6) + lane;  // 0..255
    const int r0 = pid >> 3;          // 0..31
    const int o = pid & 7;            // k-octet within BK=64 body
    const u32 aw0 = ((u32)(o >> 1) << 10) + ((u32)(o & 1) << 9) +
                    ((u32)((r0 ^ o) & 31) << 4);
    const u32 aw1 = aw0 + 4096;  // g=1 (rows 32..63)
    const float* xpA = x + (size_t)(b0 + r0) * 1024 + o * 8;
    const float* xpB = xpA + 32 * 1024;

    auto rbf6 = [&](char* buf, u32 aw, float4 xa, float4 xb) {
      float xf[8] = {xa.x, xa.y, xa.z, xa.w, xb.x, xb.y, xb.z, xb.w};
      u32 pk[6][4];
#pragma unroll
      for (int pp = 0; pp < 4; ++pp) {
        u32 lo6[6], hi6[6];
#pragma unroll
        for (int e = 0; e < 2; ++e) {
          float xv = xf[2 * pp + e];
          float t0 = C2 * xv;
          float P = __builtin_amdgcn_exp2f(t0 * xv);  // e^{-5x^2}
          float Qp = __builtin_amdgcn_exp2f(-t0);     // e^{+5x}
          float Qm = __builtin_amdgcn_exp2f(t0);      // e^{-5x}
          float PQ = P * Qp, PQm = P * Qm;
          u32* dst = e ? hi6 : lo6;
          dst[0] = __float_as_uint(PQm * Qm * T2C) + 0x8000u;
          dst[1] = __float_as_uint(PQm * T1C) + 0x8000u;
          dst[2] = __float_as_uint(P) + 0x8000u;
          dst[3] = __float_as_uint(PQ * T1C) + 0x8000u;
          dst[4] = __float_as_uint(PQ * Qp * T2C) + 0x8000u;
          dst[5] = __float_as_uint(xv) + 0x8000u;
        }
#pragma unroll
        for (int s = 0; s < 6; ++s)
          pk[s][pp] = __builtin_amdgcn_perm(hi6[s], lo6[s], 0x07060302);
      }
#pragma unroll
      for (int s = 0; s < 6; ++s) {
        uint4 v; v.x = pk[s][0]; v.y = pk[s][1]; v.z = pk[s][2]; v.w = pk[s][3];
        *(uint4*)(buf + s * 8192 + aw) = v;
      }
    };

    // prologue: body 0 -> buf0; then load x for body 1
    float4 xA0 = *(const float4*)(xpA);
    float4 xA1 = *(const float4*)(xpA + 4);
    float4 xB0 = *(const float4*)(xpB);
    float4 xB1 = *(const float4*)(xpB + 4);
    rbf6(lds, aw0, xA0, xA1);
    rbf6(lds, aw1, xB0, xB1);
    xA0 = *(const float4*)(xpA + 64);
    xA1 = *(const float4*)(xpA + 68);
    xB0 = *(const float4*)(xpB + 64);
    xB1 = *(const float4*)(xpB + 68);
    __syncthreads();  // prologue barrier

    for (int i = 0; i < 16; ++i) {
      if (i < 15) {
        char* nxt = lds + ((i + 1) & 1) * 49152;
        rbf6(nxt, aw0, xA0, xA1);
        rbf6(nxt, aw1, xB0, xB1);
        if (i < 14) {
          xA0 = *(const float4*)(xpA + (i + 2) * 64);
          xA1 = *(const float4*)(xpA + (i + 2) * 64 + 4);
          xB0 = *(const float4*)(xpB + (i + 2) * 64);
          xB1 = *(const float4*)(xpB + (i + 2) * 64 + 4);
        }
      }
      __syncthreads();  // per-body barriers
    }
    __syncthreads();  // epilogue barrier (match consumers)
  } else {
    // ================= CONSUMERS =================
    const int c = w - 4;     // 0..7
    const int wn = c & 3;    // n-quad: cols wn*32 .. +32
    const int kc = c >> 2;   // k-half (chunks 4i + kc*2 + {0,1})
    const int m = lane & 31, kh = lane >> 5;
    u32 aoff[2];
#pragma unroll
    for (int pl = 0; pl < 2; ++pl) {
      int p = kc * 2 + pl;
      aoff[pl] = (u32)(p * 1024 + kh * 512 + (((m ^ (p * 2 + kh)) & 31) << 4));
    }
    const char* bb = (const char*)wst3 + wn * 1024 + lane * 16;

    f32x16 acc[4];  // [0,1]=spline g0/g1, [2,3]=base g0/g1
#pragma unroll
    for (int i = 0; i < 4; ++i)
#pragma unroll
      for (int jj = 0; jj < 16; ++jj) acc[i][jj] = 0.f;

    __syncthreads();  // prologue barrier

    for (int i = 0; i < 16; ++i) {
      const char* cur = lds + (i & 1) * 49152;
      const char* bcb = bb + (size_t)(i * 4 + kc * 2) * 24576;
#pragma unroll
      for (int pl = 0; pl < 2; ++pl) {
        const char* bc = bcb + (size_t)pl * 24576;
        uint4 bv[6], a0[6], a1[6];
#pragma unroll
        for (int s = 0; s < 6; ++s) bv[s] = *(const uint4*)(bc + s * 4096);
#pragma unroll
        for (int s = 0; s < 6; ++s) {
          a0[s] = *(const uint4*)(cur + s * 8192 + aoff[pl]);
          a1[s] = *(const uint4*)(cur + s * 8192 + 4096 + aoff[pl]);
        }
        __builtin_amdgcn_s_setprio(1);
#pragma unroll
        for (int s = 0; s < 5; ++s) {
          acc[0] = mfma16(a0[s], bv[s], acc[0]);
          acc[1] = mfma16(a1[s], bv[s], acc[1]);
        }
        acc[2] = mfma16(a0[5], bv[5], acc[2]);
        acc[3] = mfma16(a1[5], bv[5], acc[3]);
        __builtin_amdgcn_s_setprio(0);
      }
      __syncthreads();  // per-body barriers
    }

    // ---- epilogue: kc=1 -> LDS; barrier; kc=0 merges + silu + store
    if (kc == 1) {
      char* slab = lds + wn * 16384;
#pragma unroll
      for (int a = 0; a < 4; ++a)
#pragma unroll
        for (int rq = 0; rq < 4; ++rq)
          *(float4*)(slab + a * 4096 + rq * 1024 + lane * 16) =
              make_float4(acc[a][4 * rq], acc[a][4 * rq + 1],
                          acc[a][4 * rq + 2], acc[a][4 * rq + 3]);
    }
    __syncthreads();  // epilogue barrier
    if (kc == 0) {
      const char* slab = lds + wn * 16384;
#pragma unroll
      for (int a = 0; a < 4; ++a)
#pragma unroll
        for (int rq = 0; rq < 4; ++rq) {
          float4 v = *(const float4*)(slab + a * 4096 + rq * 1024 + lane * 16);
          acc[a][4 * rq] += v.x; acc[a][4 * rq + 1] += v.y;
          acc[a][4 * rq + 2] += v.z; acc[a][4 * rq + 3] += v.w;
        }
      const int col = wn * 32 + (lane & 31);
#pragma unroll
      for (int g = 0; g < 2; ++g) {
#pragma unroll
        for (int reg = 0; reg < 16; ++reg) {
          int row = g * 32 + (reg & 3) + 8 * (reg >> 2) + 4 * (lane >> 5);
          float z = acc[2 + g][reg];
          float sv = z / (1.0f + __expf(-z));
          out[(size_t)(b0 + row) * 128 + col] = sv + acc[g][reg];
        }
      }
    }
  }
}

extern "C" void kernel_launch(void* const* d_in, const int* in_sizes, int n_in,
                              void* d_out, int out_size, void* d_ws, size_t ws_size,
                              hipStream_t stream) {
  const float* x  = (const float*)d_in[0];   // [16384][1024] f32
  const float* wb = (const float*)d_in[1];   // [1024][128]   f32
  const float* ws = (const float*)d_in[2];   // [1024][128][8] f32
  u16* wst3 = (u16*)d_ws;                    // [64][1536] granules, 1.5 MB
  float* out = (float*)d_out;                // [16384][128]  f32

  kan_prep<<<dim3(64), 256, 0, stream>>>(wb, ws, wst3);
  kan_main<<<dim3(256), 768, 0, stream>>>(x, wst3, out);
}